// Round 8
// baseline (230.486 us; speedup 1.0000x reference)
//
#include <hip/hip_runtime.h>
#include <hip/hip_fp16.h>

#define NBINS 255
#define NPAIRS 32
#define BIGF 3.0e38f

// ws layout (bytes):
//   [0        , 204800)   : prep tables (float index below)
//       [0     ,16384) : E    [64][256] fp32, tail BIGF
//       [16384 ,32768) : PE   [64][256]
//       [32768 ,36864) : M4E  [64][16] float4 {e[4j+3]} j=4t+c (idx>=255 -> BIGF)
//       [36864 ,40960) : M4P
//       [40960 ,41984) : CU16 [64][16] coarse e[16j+15], j=15 pad BIGF
//       [41984 ,43008) : CP16
//       [43008 ,51200) : W16g [64][256] fp16 PRE-SHIFTED
//   [204800  , 4399104)  : T16 [32][256][256] fp16 PRE-SHIFTED
//   [4399104 , 6496256)  : plog  [2][262144] f32   (split path)
//   [6496256 , 23273472) : pbins [16][262144] u32  (split path; word w = feats 4w..4w+3)

__global__ void ebm_prep(const float* __restrict__ edges,
                         const float* __restrict__ pair_edges,
                         const float* __restrict__ w,
                         float* __restrict__ ws) {
    int tid = blockIdx.x * blockDim.x + threadIdx.x;  // 16384 threads
    int f = tid >> 8, j = tid & 255;
    float* E  = ws;
    float* PE = ws + 16384;
    float* ME = ws + 32768;
    float* MP = ws + 36864;
    float* CU = ws + 40960;
    float* CP = ws + 41984;
    __half* W = (__half*)(ws + 43008);
    E[tid]  = (j < NBINS) ? edges[f * NBINS + j]      : BIGF;
    PE[tid] = (j < NBINS) ? pair_edges[f * NBINS + j] : BIGF;
    int src = (j < 255) ? j + 1 : 0;
    W[tid]  = __float2half(w[f * 256 + src]);
    if (j < 64) {
        int idx = 4 * j + 3;   // j=4t+c -> e[16t+4c+3]
        ME[f * 64 + j] = (idx < NBINS) ? edges[f * NBINS + idx]      : BIGF;
        MP[f * 64 + j] = (idx < NBINS) ? pair_edges[f * NBINS + idx] : BIGF;
    }
    if (j < 16) {
        CU[f * 16 + j] = (j < 15) ? edges[f * NBINS + 16 * j + 15]      : BIGF;
        CP[f * 16 + j] = (j < 15) ? pair_edges[f * NBINS + 16 * j + 15] : BIGF;
    }
}

__global__ void ebm_prep_tables(const float* __restrict__ tables,
                                unsigned short* __restrict__ o) {
    int i = blockIdx.x * blockDim.x + threadIdx.x;    // 2097152 threads
    int b = i & 255, a = (i >> 8) & 255, p = i >> 16;
    int ra = (a < 255) ? a + 1 : 0;
    int rb = (b < 255) ? b + 1 : 0;
    o[i] = __half_as_ushort(__float2half(tables[(p << 16) + (ra << 8) + rb]));
}

// ================= SPLIT PATH: kernel A — binning (half features/block) =====
// 512 blocks x 1024 threads; block b: rows (b>>1)*1024.., feature half b&1.
// LDS = 80 KiB -> 2 blocks/CU. Plain __launch_bounds__(1024): ",N" makes the
// compiler budget VGPR=256/N -> spill (proven v2/v7). Must stay <=64 VGPR.
// v9: (1) x preloaded in 4-float4 register batches -> L2 line lifetime drops
// from ~8 loop bodies to ~0 (fixes the 150 MB x re-fetch seen in v7/v8);
// (2) pbins/plog written with nontemporal stores -> no L2 allocation, no
// eviction pressure on x lines.
__global__ __launch_bounds__(1024) void ebm_bin(
    const float* __restrict__ x,
    const float* __restrict__ ws,
    float*       __restrict__ plog,
    unsigned*    __restrict__ pbins) {

    __shared__ float  sE[8192];     // unary fine [32][256]
    __shared__ float  sPE[8192];    // pair fine
    __shared__ float4 sME[512];     // unary mid [32][16]
    __shared__ float4 sMP[512];     // pair mid

    int tid = threadIdx.x;
    int h = blockIdx.x & 1;                      // feature half (SGPR)
    int rowbase = (blockIdx.x >> 1) * 1024;
    {
        const float4* w4 = (const float4*)ws;
        float4* dE = (float4*)sE;
        float4* dP = (float4*)sPE;
        for (int i = tid; i < 2048; i += 1024) {
            dE[i] = w4[h * 2048 + i];            // E half
            dP[i] = w4[4096 + h * 2048 + i];     // PE half
        }
        if (tid < 512) {
            sME[tid] = w4[8192 + h * 512 + tid];
            sMP[tid] = w4[9216 + h * 512 + tid];
        }
    }
    const float*  CU = ws + 40960 + h * 512;     // 32 feats x 16
    const float*  CP = ws + 41984 + h * 512;
    const __half* Wg = (const __half*)(ws + 43008);

    __syncthreads();

    int row = rowbase + tid;
    const float4* x4  = (const float4*)x + row * 16 + h * 8;
    const float4* sE4 = (const float4*)sE;
    const float4* sP4 = (const float4*)sPE;

    float acc = 0.f;

#pragma unroll
    for (int q = 0; q < 2; ++q) {
        // ---- batch-load 64B of x: 4 back-to-back dwordx4, line touched 4x
        //      within the load window (no long-lived L2 line) ----
        float4 xr[4];
#pragma unroll
        for (int i = 0; i < 4; ++i) xr[i] = x4[q * 4 + i];

#pragma unroll
        for (int g = 0; g < 4; ++g) {
            int fl = q * 4 + g;                   // local float4 group 0..7
            int fb = 4 * fl;                      // local feature base
            float xf[4] = {xr[g].x, xr[g].y, xr[g].z, xr[g].w};

            // ---- unary coarse (SGPR compares) ----
            int t[4];
#pragma unroll
            for (int j = 0; j < 4; ++j) {
                const float* cu = CU + (fb + j) * 16;
                int tt = 0;
#pragma unroll
                for (int k = 0; k < 15; ++k) tt += (xf[j] >= cu[k]);
                t[j] = tt;
            }
            // ---- pair coarse ----
            int t2[4];
#pragma unroll
            for (int j = 0; j < 4; ++j) {
                const float* cp = CP + (fb + j) * 16;
                int tt = 0;
#pragma unroll
                for (int k = 0; k < 15; ++k) tt += (xf[j] >= cp[k]);
                t2[j] = tt;
            }
            // ---- mids (LDS) ----
            float4 mu[4], mp[4];
#pragma unroll
            for (int j = 0; j < 4; ++j) mu[j] = sME[(fb + j) * 16 + t[j]];
#pragma unroll
            for (int j = 0; j < 4; ++j) mp[j] = sMP[(fb + j) * 16 + t2[j]];
            // ---- fines (LDS) ----
            int lo[4], lo2[4];
            float4 fu[4], fp[4];
#pragma unroll
            for (int j = 0; j < 4; ++j) {
                int m = (xf[j] >= mu[j].x) + (xf[j] >= mu[j].y) + (xf[j] >= mu[j].z);
                lo[j] = 4 * t[j] + m;
                fu[j] = sE4[(fb + j) * 64 + lo[j]];
            }
#pragma unroll
            for (int j = 0; j < 4; ++j) {
                int m = (xf[j] >= mp[j].x) + (xf[j] >= mp[j].y) + (xf[j] >= mp[j].z);
                lo2[j] = 4 * t2[j] + m;
                fp[j] = sP4[(fb + j) * 64 + lo2[j]];
            }
            // ---- unary consume -> W gather (global fp16, latency-tolerant) ----
#pragma unroll
            for (int j = 0; j < 4; ++j) {
                int c = 4 * lo[j] + (xf[j] >= fu[j].x) + (xf[j] >= fu[j].y) +
                        (xf[j] >= fu[j].z) + (xf[j] >= fu[j].w);
                acc += __half2float(Wg[(h * 32 + fb + j) * 256 + c]);
            }
            // ---- pair consume -> pack word, nontemporal store ----
            unsigned pword = 0;
#pragma unroll
            for (int j = 0; j < 4; ++j) {
                int c2 = 4 * lo2[j] + (xf[j] >= fp[j].x) + (xf[j] >= fp[j].y) +
                         (xf[j] >= fp[j].z) + (xf[j] >= fp[j].w);
                pword |= (unsigned)c2 << (8 * j);
            }
            __builtin_nontemporal_store(pword, &pbins[(h * 8 + fl) * 262144 + row]);
        }
    }

    __builtin_nontemporal_store(acc, &plog[h * 262144 + row]);
}

// ================= SPLIT PATH: kernel B — pair gathers + combine ============
// 256 blocks x 1024 threads, no LDS -> max occupancy; pure gather engine.
__global__ __launch_bounds__(1024) void ebm_pairs(
    const int*      __restrict__ pairs,
    const float*    __restrict__ tables_f32,
    const float*    __restrict__ bias,
    const float*    __restrict__ plog,
    const unsigned* __restrict__ pbins,
    const __half*   __restrict__ T16,
    int useT16,
    float*          __restrict__ out) {

    int row = blockIdx.x * 1024 + threadIdx.x;
    float acc = plog[row] + plog[262144 + row] + bias[0];

    if (useT16) {
#pragma unroll
        for (int p = 0; p < NPAIRS; ++p) {
            int a = pairs[2 * p], b = pairs[2 * p + 1];        // uniform s_load
            unsigned wa = pbins[(a >> 2) * 262144 + row];      // coalesced
            unsigned wb = pbins[(b >> 2) * 262144 + row];
            int li = (wa >> ((a & 3) * 8)) & 255;
            int ri = (wb >> ((b & 3) * 8)) & 255;
            acc += __half2float(T16[(p << 16) + (li << 8) + ri]);
        }
    } else {
#pragma unroll
        for (int p = 0; p < NPAIRS; ++p) {
            int a = pairs[2 * p], b = pairs[2 * p + 1];
            unsigned wa = pbins[(a >> 2) * 262144 + row];
            unsigned wb = pbins[(b >> 2) * 262144 + row];
            int li = (wa >> ((a & 3) * 8)) & 255;
            int ri = (wb >> ((b & 3) * 8)) & 255;
            int lb = (li < 255) ? li + 1 : 0;
            int rb = (ri < 255) ? ri + 1 : 0;
            acc += tables_f32[(p << 16) + (lb << 8) + rb];
        }
    }

    out[row] = 1.0f / (1.0f + __expf(-acc));
}

// ================= FALLBACK: v3 mono kernel (101 us verified) ===============
__device__ __forceinline__ unsigned pick16(const unsigned* pw, int s) {
    unsigned v01 = (s & 1) ? pw[1]  : pw[0];
    unsigned v23 = (s & 1) ? pw[3]  : pw[2];
    unsigned v45 = (s & 1) ? pw[5]  : pw[4];
    unsigned v67 = (s & 1) ? pw[7]  : pw[6];
    unsigned v89 = (s & 1) ? pw[9]  : pw[8];
    unsigned vab = (s & 1) ? pw[11] : pw[10];
    unsigned vcd = (s & 1) ? pw[13] : pw[12];
    unsigned vef = (s & 1) ? pw[15] : pw[14];
    unsigned w0 = (s & 2) ? v23 : v01;
    unsigned w1 = (s & 2) ? v67 : v45;
    unsigned w2 = (s & 2) ? vab : v89;
    unsigned w3 = (s & 2) ? vef : vcd;
    unsigned u0 = (s & 4) ? w1 : w0;
    unsigned u1 = (s & 4) ? w3 : w2;
    return (s & 8) ? u1 : u0;
}

__global__ __launch_bounds__(1024, 4) void ebm_main_mono(
    const float* __restrict__ x,
    const int*   __restrict__ pairs,
    const float* __restrict__ tables_f32,
    const float* __restrict__ bias,
    const float* __restrict__ ws,
    const __half* __restrict__ T16,
    int useT16,
    float*       __restrict__ out) {

    __shared__ float  sE[16384];
    __shared__ float  sPE[16384];
    __shared__ float4 sME[1024];
    __shared__ float4 sMP[1024];

    int tid = threadIdx.x;
    {
        const float4* w4 = (const float4*)ws;
        float4* dE = (float4*)sE;
        float4* dP = (float4*)sPE;
        for (int i = tid; i < 4096; i += 1024) {
            dE[i] = w4[i];
            dP[i] = w4[4096 + i];
        }
        sME[tid] = w4[8192 + tid];
        sMP[tid] = w4[9216 + tid];
    }
    const float*  CU = ws + 40960;
    const float*  CP = ws + 41984;
    const __half* Wg = (const __half*)(ws + 43008);
    float bias0 = bias[0];

    __syncthreads();

    int row = blockIdx.x * 1024 + tid;
    const float4* x4  = (const float4*)x + row * 16;
    const float4* sE4 = (const float4*)sE;
    const float4* sP4 = (const float4*)sPE;

    float acc = 0.f;
    unsigned pw[16];

    float4 xg = x4[0];
#pragma unroll
    for (int g = 0; g < 16; ++g) {
        int fb = 4 * g;
        float4 xnext = xg;
        if (g < 15) xnext = x4[g + 1];
        float xf[4] = {xg.x, xg.y, xg.z, xg.w};

        int t[4];
#pragma unroll
        for (int j = 0; j < 4; ++j) {
            const float* cu = CU + (fb + j) * 16;
            int tt = 0;
#pragma unroll
            for (int k = 0; k < 15; ++k) tt += (xf[j] >= cu[k]);
            t[j] = tt;
        }
        int t2[4];
#pragma unroll
        for (int j = 0; j < 4; ++j) {
            const float* cp = CP + (fb + j) * 16;
            int tt = 0;
#pragma unroll
            for (int k = 0; k < 15; ++k) tt += (xf[j] >= cp[k]);
            t2[j] = tt;
        }
        float4 mu[4], mp[4];
#pragma unroll
        for (int j = 0; j < 4; ++j) mu[j] = sME[(fb + j) * 16 + t[j]];
#pragma unroll
        for (int j = 0; j < 4; ++j) mp[j] = sMP[(fb + j) * 16 + t2[j]];
        int lo[4], lo2[4];
        float4 fu[4], fp[4];
#pragma unroll
        for (int j = 0; j < 4; ++j) {
            int m = (xf[j] >= mu[j].x) + (xf[j] >= mu[j].y) + (xf[j] >= mu[j].z);
            lo[j] = 4 * t[j] + m;
            fu[j] = sE4[(fb + j) * 64 + lo[j]];
        }
#pragma unroll
        for (int j = 0; j < 4; ++j) {
            int m = (xf[j] >= mp[j].x) + (xf[j] >= mp[j].y) + (xf[j] >= mp[j].z);
            lo2[j] = 4 * t2[j] + m;
            fp[j] = sP4[(fb + j) * 64 + lo2[j]];
        }
#pragma unroll
        for (int j = 0; j < 4; ++j) {
            int c = 4 * lo[j] + (xf[j] >= fu[j].x) + (xf[j] >= fu[j].y) +
                    (xf[j] >= fu[j].z) + (xf[j] >= fu[j].w);
            acc += __half2float(Wg[(fb + j) * 256 + c]);
        }
        unsigned pword = 0;
#pragma unroll
        for (int j = 0; j < 4; ++j) {
            int c2 = 4 * lo2[j] + (xf[j] >= fp[j].x) + (xf[j] >= fp[j].y) +
                     (xf[j] >= fp[j].z) + (xf[j] >= fp[j].w);
            pword |= (unsigned)c2 << (8 * j);
        }
        pw[g] = pword;
        xg = xnext;
    }

    if (useT16) {
#pragma unroll
        for (int p = 0; p < NPAIRS; ++p) {
            int a = pairs[2 * p], b = pairs[2 * p + 1];
            unsigned wa = pick16(pw, a >> 2);
            unsigned wb = pick16(pw, b >> 2);
            int li = (wa >> ((a & 3) * 8)) & 255;
            int ri = (wb >> ((b & 3) * 8)) & 255;
            acc += __half2float(T16[(p << 16) + (li << 8) + ri]);
        }
    } else {
#pragma unroll
        for (int p = 0; p < NPAIRS; ++p) {
            int a = pairs[2 * p], b = pairs[2 * p + 1];
            unsigned wa = pick16(pw, a >> 2);
            unsigned wb = pick16(pw, b >> 2);
            int li = (wa >> ((a & 3) * 8)) & 255;
            int ri = (wb >> ((b & 3) * 8)) & 255;
            int lb = (li < 255) ? li + 1 : 0;
            int rb = (ri < 255) ? ri + 1 : 0;
            acc += tables_f32[(p << 16) + (lb << 8) + rb];
        }
    }

    out[row] = 1.0f / (1.0f + __expf(-(acc + bias0)));
}

extern "C" void kernel_launch(void* const* d_in, const int* in_sizes, int n_in,
                              void* d_out, int out_size, void* d_ws, size_t ws_size,
                              hipStream_t stream) {
    const float* x          = (const float*)d_in[0];
    const float* edges      = (const float*)d_in[1];
    const float* w          = (const float*)d_in[2];
    const float* pair_edges = (const float*)d_in[3];
    const int*   pairs      = (const int*)d_in[4];
    const float* tables     = (const float*)d_in[5];
    const float* bias       = (const float*)d_in[6];
    float* out = (float*)d_out;
    float* ws  = (float*)d_ws;

    int useT16  = (ws_size >= (size_t)4399104) ? 1 : 0;
    int useSplit = (ws_size >= (size_t)23273472) ? 1 : 0;
    __half*   T16   = (__half*)((char*)d_ws + 204800);
    float*    plog  = (float*)((char*)d_ws + 4399104);
    unsigned* pbins = (unsigned*)((char*)d_ws + 6496256);

    ebm_prep<<<64, 256, 0, stream>>>(edges, pair_edges, w, ws);
    if (useT16) {
        ebm_prep_tables<<<2048, 1024, 0, stream>>>(tables, (unsigned short*)T16);
    }
    if (useSplit) {
        ebm_bin<<<512, 1024, 0, stream>>>(x, ws, plog, pbins);
        ebm_pairs<<<256, 1024, 0, stream>>>(pairs, tables, bias, plog, pbins,
                                            T16, useT16, out);
    } else {
        ebm_main_mono<<<256, 1024, 0, stream>>>(x, pairs, tables, bias, ws,
                                                T16, useT16, out);
    }
}

// Round 9
// 193.466 us; speedup vs baseline: 1.1914x; 1.1914x over previous
//
#include <hip/hip_runtime.h>
#include <hip/hip_fp16.h>

#define NBINS 255
#define NPAIRS 32
#define BIGF 3.0e38f

// ws layout (float index):
//   [0     ,16384) : E    [64][256] fp32, tail BIGF
//   [16384 ,32768) : PE   [64][256]
//   [32768 ,36864) : M4E  [64][16] float4 {e[4j+3]} j=4t+c  (idx>=255 -> BIGF)
//   [36864 ,40960) : M4P
//   [40960 ,41984) : CU16 [64][16] coarse e[16j+15], j=15 pad BIGF
//   [41984 ,43008) : CP16
//   [43008 ,51200) : W16g [64][256] fp16 PRE-SHIFTED (8192 floats of storage)
//   byte 204800 .. : T16  [32][256][256] fp16 PRE-SHIFTED (needs ws >= 4399104 B)
//
// ROUND-0 KERNEL RESTORED (best measured: 193.5 us headline, ebm_main 101-104).
// Session ledger (9 structural experiments, all regressions or neutral):
//  - 2 thr/row + pair tables via L2 (v2): fill-bound 115 us, FETCH 200 MB
//  - 8-wide ILP (v3): neutral 101 us
//  - coarse via global vmcnt domain (v4): 172 us (VMEM on critical path)
//  - inverse-CDF grid (v5): 217 us (scratch spill from divergent loop)
//  - manual 2-stage pipeline (v6): 174 us (worse schedule than compiler's)
//  - split bin/pairs kernels (v7-v9): bin-phase stuck at ~100 us, fill-bound
//    at ~2.5 TB/s L2-fill (FETCH 220-302 MB); split adds ~20 us pairs kernel.
// Conclusion: mono = latency-bound at 16 waves/CU (LDS-capped); raising
// occupancy forces table splitting which converts the kernel to fill-bound at
// the same ~100 us wall. __launch_bounds__(1024,N>=4) triggers VGPR=256/N
// budget -> spill; plain (1024) allocates 52 VGPR, no spill.

__global__ void ebm_prep(const float* __restrict__ edges,
                         const float* __restrict__ pair_edges,
                         const float* __restrict__ w,
                         float* __restrict__ ws) {
    int tid = blockIdx.x * blockDim.x + threadIdx.x;  // 16384 threads
    int f = tid >> 8, j = tid & 255;
    float* E  = ws;
    float* PE = ws + 16384;
    float* ME = ws + 32768;
    float* MP = ws + 36864;
    float* CU = ws + 40960;
    float* CP = ws + 41984;
    __half* W = (__half*)(ws + 43008);
    E[tid]  = (j < NBINS) ? edges[f * NBINS + j]      : BIGF;
    PE[tid] = (j < NBINS) ? pair_edges[f * NBINS + j] : BIGF;
    int src = (j < 255) ? j + 1 : 0;
    W[tid]  = __float2half(w[f * 256 + src]);
    if (j < 64) {
        int idx = 4 * j + 3;   // j=4t+c -> e[16t+4c+3]
        ME[f * 64 + j] = (idx < NBINS) ? edges[f * NBINS + idx]      : BIGF;
        MP[f * 64 + j] = (idx < NBINS) ? pair_edges[f * NBINS + idx] : BIGF;
    }
    if (j < 16) {
        CU[f * 16 + j] = (j < 15) ? edges[f * NBINS + 16 * j + 15]      : BIGF;
        CP[f * 16 + j] = (j < 15) ? pair_edges[f * NBINS + 16 * j + 15] : BIGF;
    }
}

__global__ void ebm_prep_tables(const float* __restrict__ tables,
                                unsigned short* __restrict__ o) {
    int i = blockIdx.x * blockDim.x + threadIdx.x;    // 2097152 threads
    int b = i & 255, a = (i >> 8) & 255, p = i >> 16;
    int ra = (a < 255) ? a + 1 : 0;
    int rb = (b < 255) ? b + 1 : 0;
    o[i] = __half_as_ushort(__float2half(tables[(p << 16) + (ra << 8) + rb]));
}

// uniform 16-way register select: s is wave-uniform -> 15 v_cndmask w/ scalar masks
__device__ __forceinline__ unsigned pick16(const unsigned* pw, int s) {
    unsigned v01 = (s & 1) ? pw[1]  : pw[0];
    unsigned v23 = (s & 1) ? pw[3]  : pw[2];
    unsigned v45 = (s & 1) ? pw[5]  : pw[4];
    unsigned v67 = (s & 1) ? pw[7]  : pw[6];
    unsigned v89 = (s & 1) ? pw[9]  : pw[8];
    unsigned vab = (s & 1) ? pw[11] : pw[10];
    unsigned vcd = (s & 1) ? pw[13] : pw[12];
    unsigned vef = (s & 1) ? pw[15] : pw[14];
    unsigned w0 = (s & 2) ? v23 : v01;
    unsigned w1 = (s & 2) ? v67 : v45;
    unsigned w2 = (s & 2) ? vab : v89;
    unsigned w3 = (s & 2) ? vef : vcd;
    unsigned u0 = (s & 4) ? w1 : w0;
    unsigned u1 = (s & 4) ? w3 : w2;
    return (s & 8) ? u1 : u0;
}

__global__ __launch_bounds__(1024) void ebm_main(
    const float* __restrict__ x,
    const int*   __restrict__ pairs,
    const float* __restrict__ tables_f32,
    const float* __restrict__ bias,
    const float* __restrict__ ws,
    const __half* __restrict__ T16,
    int useT16,
    float*       __restrict__ out) {

    // exactly 160 KiB
    __shared__ float  sE[16384];
    __shared__ float  sPE[16384];
    __shared__ float4 sME[1024];
    __shared__ float4 sMP[1024];

    int tid = threadIdx.x;
    {
        const float4* w4 = (const float4*)ws;
        float4* dE = (float4*)sE;
        float4* dP = (float4*)sPE;
        for (int i = tid; i < 4096; i += 1024) {
            dE[i] = w4[i];
            dP[i] = w4[4096 + i];
        }
        if (tid < 1024) {
            sME[tid] = w4[8192 + tid];
            sMP[tid] = w4[9216 + tid];
        }
    }
    const float*  CU = ws + 40960;
    const float*  CP = ws + 41984;
    const __half* Wg = (const __half*)(ws + 43008);
    float bias0 = bias[0];

    __syncthreads();

    int row = blockIdx.x * 1024 + tid;       // 256 blocks x 1024 threads
    const float4* x4 = (const float4*)x + row * 16;
    const float4* sE4 = (const float4*)sE;
    const float4* sP4 = (const float4*)sPE;

    float acc = 0.f;
    unsigned pw[16];

    float4 xg = x4[0];
#pragma unroll
    for (int g = 0; g < 16; ++g) {
        float4 xnext = xg;
        if (g < 15) xnext = x4[g + 1];
        float xf[4] = {xg.x, xg.y, xg.z, xg.w};

        // ---- unary: coarse (SGPR compares) ----
        int t[4];
#pragma unroll
        for (int j = 0; j < 4; ++j) {
            const float* cu = CU + (4 * g + j) * 16;   // uniform -> s_load
            int tt = 0;
#pragma unroll
            for (int k = 0; k < 15; ++k) tt += (xf[j] >= cu[k]);
            t[j] = tt;
        }
        // ---- pair: coarse ----
        int t2[4];
#pragma unroll
        for (int j = 0; j < 4; ++j) {
            const float* cp = CP + (4 * g + j) * 16;
            int tt = 0;
#pragma unroll
            for (int k = 0; k < 15; ++k) tt += (xf[j] >= cp[k]);
            t2[j] = tt;
        }
        // ---- mids (LDS, conflict-free: bank grp = t mod 8 + broadcasts) ----
        float4 mu[4], mp[4];
#pragma unroll
        for (int j = 0; j < 4; ++j) mu[j] = sME[(4 * g + j) * 16 + t[j]];
#pragma unroll
        for (int j = 0; j < 4; ++j) mp[j] = sMP[(4 * g + j) * 16 + t2[j]];
        // ---- fine loads ----
        int lo[4], lo2[4];
        float4 fu[4], fp[4];
#pragma unroll
        for (int j = 0; j < 4; ++j) {
            int m = (xf[j] >= mu[j].x) + (xf[j] >= mu[j].y) + (xf[j] >= mu[j].z);
            lo[j] = 4 * t[j] + m;
            fu[j] = sE4[(4 * g + j) * 64 + lo[j]];
        }
#pragma unroll
        for (int j = 0; j < 4; ++j) {
            int m = (xf[j] >= mp[j].x) + (xf[j] >= mp[j].y) + (xf[j] >= mp[j].z);
            lo2[j] = 4 * t2[j] + m;
            fp[j] = sP4[(4 * g + j) * 64 + lo2[j]];
        }
        // ---- unary consume -> W gather (global fp16, <=8 lines/wave) ----
#pragma unroll
        for (int j = 0; j < 4; ++j) {
            int c = 4 * lo[j] + (xf[j] >= fu[j].x) + (xf[j] >= fu[j].y) +
                    (xf[j] >= fu[j].z) + (xf[j] >= fu[j].w);
            acc += __half2float(Wg[(4 * g + j) * 256 + c]);
        }
        // ---- pair consume -> pack 8-bit ----
        unsigned pword = 0;
#pragma unroll
        for (int j = 0; j < 4; ++j) {
            int c2 = 4 * lo2[j] + (xf[j] >= fp[j].x) + (xf[j] >= fp[j].y) +
                     (xf[j] >= fp[j].z) + (xf[j] >= fp[j].w);
            pword |= (unsigned)c2 << (8 * j);
        }
        pw[g] = pword;
        xg = xnext;
    }

    // ---- pair table gathers: per-lane-owned, no exchange ----
    if (useT16) {
#pragma unroll
        for (int p = 0; p < NPAIRS; ++p) {
            int a = pairs[2 * p], b = pairs[2 * p + 1];   // uniform
            unsigned wa = pick16(pw, a >> 2);
            unsigned wb = pick16(pw, b >> 2);
            int li = (wa >> ((a & 3) * 8)) & 255;
            int ri = (wb >> ((b & 3) * 8)) & 255;
            acc += __half2float(T16[(p << 16) + (li << 8) + ri]);
        }
    } else {
#pragma unroll
        for (int p = 0; p < NPAIRS; ++p) {
            int a = pairs[2 * p], b = pairs[2 * p + 1];
            unsigned wa = pick16(pw, a >> 2);
            unsigned wb = pick16(pw, b >> 2);
            int li = (wa >> ((a & 3) * 8)) & 255;
            int ri = (wb >> ((b & 3) * 8)) & 255;
            int lb = (li < 255) ? li + 1 : 0;
            int rb = (ri < 255) ? ri + 1 : 0;
            acc += tables_f32[(p << 16) + (lb << 8) + rb];
        }
    }

    out[row] = 1.0f / (1.0f + __expf(-(acc + bias0)));
}

extern "C" void kernel_launch(void* const* d_in, const int* in_sizes, int n_in,
                              void* d_out, int out_size, void* d_ws, size_t ws_size,
                              hipStream_t stream) {
    const float* x          = (const float*)d_in[0];
    const float* edges      = (const float*)d_in[1];
    const float* w          = (const float*)d_in[2];
    const float* pair_edges = (const float*)d_in[3];
    const int*   pairs      = (const int*)d_in[4];
    const float* tables     = (const float*)d_in[5];
    const float* bias       = (const float*)d_in[6];
    float* out = (float*)d_out;
    float* ws  = (float*)d_ws;

    int useT16 = (ws_size >= (size_t)4399104) ? 1 : 0;
    __half* T16 = (__half*)((char*)d_ws + 204800);

    ebm_prep<<<64, 256, 0, stream>>>(edges, pair_edges, w, ws);
    if (useT16) {
        ebm_prep_tables<<<2048, 1024, 0, stream>>>(tables, (unsigned short*)T16);
    }
    ebm_main<<<256, 1024, 0, stream>>>(x, pairs, tables, bias, ws, T16, useT16, out);
}